// Round 8
// baseline (662.276 us; speedup 1.0000x reference)
//
#include <hip/hip_runtime.h>
#include <hip/hip_fp16.h>
#include <hip/hip_cooperative_groups.h>

namespace cg = cooperative_groups;

typedef _Float16 half8 __attribute__((ext_vector_type(8)));
typedef float floatx4 __attribute__((ext_vector_type(4)));

#define OSH 13            // src-octile shift for csr ordering (locality in gather)
#define BN  128           // nodes per bucket
#define BSH 7             // log2(BN)

// ---------------- QR: 3x3 Householder, LAPACK sgeqrf/sorgqr convention ----------------
__device__ inline void qr3_q(const double A[3][3], double Q[3][3]){
  double a[3][3];
#pragma unroll
  for (int r = 0; r < 3; r++)
#pragma unroll
    for (int c = 0; c < 3; c++) a[r][c] = A[r][c];

  double v1[3] = {1.0, 0.0, 0.0};
  double tau1 = 0.0;
  {
    double xn2 = a[1][0]*a[1][0] + a[2][0]*a[2][0];
    if (xn2 != 0.0){
      double alpha = a[0][0];
      double beta = -copysign(sqrt(alpha*alpha + xn2), alpha);
      tau1 = (beta - alpha) / beta;
      double inv = 1.0 / (alpha - beta);
      v1[1] = a[1][0] * inv;
      v1[2] = a[2][0] * inv;
#pragma unroll
      for (int c = 1; c < 3; c++){
        double w = a[0][c] + v1[1]*a[1][c] + v1[2]*a[2][c];
        double tw = tau1 * w;
        a[0][c] -= tw;
        a[1][c] -= tw * v1[1];
        a[2][c] -= tw * v1[2];
      }
    }
  }
  double tau2 = 0.0, v2 = 0.0;
  {
    double x2 = a[2][1];
    if (x2 != 0.0){
      double alpha = a[1][1];
      double beta = -copysign(sqrt(alpha*alpha + x2*x2), alpha);
      tau2 = (beta - alpha) / beta;
      v2 = x2 / (alpha - beta);
    }
  }
  double M[3][3] = {{1.0, 0.0, 0.0},
                    {0.0, 1.0 - tau2, -tau2*v2},
                    {0.0, -tau2*v2, 1.0 - tau2*v2*v2}};
#pragma unroll
  for (int c = 0; c < 3; c++){
    double w = v1[0]*M[0][c] + v1[1]*M[1][c] + v1[2]*M[2][c];
#pragma unroll
    for (int r = 0; r < 3; r++)
      Q[r][c] = M[r][c] - tau1 * v1[r] * w;
  }
}

// ---------------- SE(3) per-node epilogue from a local ds[13] ----------------
__device__ inline void se3_node_ds(int n, const float ds[13],
                                   const float* __restrict__ bc, const float* __restrict__ bR,
                                   const float* __restrict__ bt, const float* __restrict__ pos_in,
                                   float* __restrict__ pos_o, float* __restrict__ R_o,
                                   float* __restrict__ t_o, int layer){
  double A[3][3], Q[3][3];
#pragma unroll
  for (int r = 0; r < 3; r++)
#pragma unroll
    for (int c = 0; c < 3; c++)
      A[r][c] = (double)ds[1 + r*3 + c] + (double)bR[r*3 + c];
  qr3_q(A, Q);

  double pd = (double)ds[0] + (double)bc[0];
#pragma unroll
  for (int c = 0; c < 3; c++){
    double base = (layer == 0) ? (double)pos_in[n*3 + c] : (double)pos_o[n*3 + c];
    pos_o[n*3 + c] = (float)(base + pd);
  }

  if (layer == 0){
#pragma unroll
    for (int r = 0; r < 3; r++)
#pragma unroll
      for (int c = 0; c < 3; c++)
        R_o[n*9 + r*3 + c] = (float)Q[r][c];
  } else {
    double Rold[3][3];
#pragma unroll
    for (int r = 0; r < 3; r++)
#pragma unroll
      for (int c = 0; c < 3; c++)
        Rold[r][c] = (double)R_o[n*9 + r*3 + c];
#pragma unroll
    for (int r = 0; r < 3; r++)
#pragma unroll
      for (int c = 0; c < 3; c++){
        double s = Q[r][0]*Rold[0][c] + Q[r][1]*Rold[1][c] + Q[r][2]*Rold[2][c];
        R_o[n*9 + r*3 + c] = (float)s;
      }
  }
#pragma unroll
  for (int c = 0; c < 3; c++){
    double base = (layer == 0) ? 0.0 : (double)t_o[n*3 + c];
    t_o[n*3 + c] = (float)(base + (double)ds[10 + c] + (double)bt[c]);
  }
}

// ================= shared device bodies (used by mega kernel AND fallback) =============

__device__ __forceinline__ void dev_cvt_chunk(int c, const float* __restrict__ x,
                                              _Float16* __restrict__ o, int N){
  int n = c >> 4;
  half8 h = {};
  if (n < N){
    const float* p = x + (size_t)c*8;
    float4 f0 = *(const float4*)p;
    float4 f1 = *(const float4*)(p + 4);
    h[0]=(_Float16)f0.x; h[1]=(_Float16)f0.y; h[2]=(_Float16)f0.z; h[3]=(_Float16)f0.w;
    h[4]=(_Float16)f1.x; h[5]=(_Float16)f1.y; h[6]=(_Float16)f1.z; h[7]=(_Float16)f1.w;
  }
  *(half8*)(o + (size_t)c*8) = h;
}

__device__ __forceinline__ void dev_prep_elem(int t,
    const float* __restrict__ Wl, const float* __restrict__ Wf,
    const float* __restrict__ Wc, const float* __restrict__ WR,
    const float* __restrict__ Wt, _Float16* __restrict__ wTx, _Float16* __restrict__ wHd){
  if (t < 4*128*128){
    int l = t >> 14;
    int n = (t >> 7) & 127;
    int k = t & 127;
    const float* W = (l < 3) ? (Wl + (size_t)l*16384) : Wf;
    wTx[t] = (_Float16)W[k*128 + n];
  } else if (t < 4*128*128 + 3*16*128){
    int u = t - 4*128*128;
    int l = u >> 11;
    int r = u & 2047;
    int n = r >> 7;
    int k = r & 127;
    float v = 0.f;
    if (n == 0)      v = Wc[(size_t)l*128 + k];
    else if (n < 10) v = WR[(size_t)l*1152 + k*9 + (n-1)];
    else if (n < 13) v = Wt[(size_t)l*384 + k*3 + (n-10)];
    wHd[u] = (_Float16)v;
  }
}

__device__ __forceinline__ void dev_bin_block(int bb,
    const int* __restrict__ src, const int* __restrict__ dst,
    int E, int nbuck, int capB, int* __restrict__ cursor, int* __restrict__ binned,
    int* __restrict__ cnt, int* __restrict__ segbase){
  const int tid = threadIdx.x;
  for (int t = tid; t < nbuck; t += 256) cnt[t] = 0;
  __syncthreads();
  const int e0 = bb*4096 + tid;
  int pk[16], bk[16];
#pragma unroll
  for (int j = 0; j < 16; j++){
    int e = e0 + j*256;
    if (e < E){
      int d = dst[e], s = src[e];
      bk[j] = d >> BSH;
      pk[j] = (s << BSH) | (d & (BN-1));
      atomicAdd(&cnt[bk[j]], 1);
    } else bk[j] = -1;
  }
  __syncthreads();
  for (int t = tid; t < nbuck; t += 256){
    int c = cnt[t];
    if (c > 0) segbase[t] = t*capB + atomicAdd(&cursor[t], c);
    cnt[t] = 0;
  }
  __syncthreads();
#pragma unroll
  for (int j = 0; j < 16; j++){
    if (bk[j] >= 0){
      int ord = atomicAdd(&cnt[bk[j]], 1);
      binned[segbase[bk[j]] + ord] = pk[j];
    }
  }
  __syncthreads();   // protect cnt/segbase for next grid-stride iteration
}

__device__ __forceinline__ void dev_build_block(int b,
    const int* __restrict__ binned, const int* __restrict__ cursor,
    int N, int capB, int capC, int2* __restrict__ sd, int* __restrict__ csr,
    int* __restrict__ deg2, int* __restrict__ lst2, int* __restrict__ cnt2,
    int* __restrict__ scn){
  const int tid = threadIdx.x;
  for (int t = tid; t < BN*8; t += 256){ deg2[t] = 0; cnt2[t] = 0; }
  __syncthreads();
  const int nE = cursor[b];
  const int gbase = b*capB;
  for (int i = tid; i < nE; i += 256){
    int v = binned[gbase + i];
    int s = v >> BSH;
    int o = s >> OSH; if (o > 7) o = 7;
    atomicAdd(&deg2[((v & (BN-1)) << 3) + o], 1);
  }
  __syncthreads();
  int d0 = 0, p0 = 0;
  if (tid < BN){
#pragma unroll
    for (int o = 0; o < 8; o++) d0 += deg2[(tid << 3) + o];
    p0 = (d0+7)&~7;
    scn[tid] = p0;
  }
  __syncthreads();
#pragma unroll
  for (int off = 1; off < BN; off <<= 1){
    int add = 0;
    if (tid < BN && tid >= off) add = scn[tid-off];
    __syncthreads();
    if (tid < BN) scn[tid] += add;
    __syncthreads();
  }
  const int csrb = b*capC;
  int ex = 0;
  if (tid < BN){
    ex = scn[tid] - p0;
    int off0 = ex;
#pragma unroll
    for (int o = 0; o < 8; o++){ lst2[(tid << 3) + o] = off0; off0 += deg2[(tid << 3) + o]; }
    int n0 = b*BN + tid;
    if (n0 < N) sd[n0] = make_int2(csrb + ex, (d0 << 16) | p0);
  }
  __syncthreads();
  for (int i = tid; i < nE; i += 256){
    int v = binned[gbase + i];
    int dl = v & (BN-1), s = v >> BSH;
    int o = s >> OSH; if (o > 7) o = 7;
    int ord = atomicAdd(&cnt2[(dl << 3) + o], 1);
    csr[csrb + lst2[(dl << 3) + o] + ord] = s;
  }
  __syncthreads();
  if (tid < BN){
    for (int j = d0; j < p0; j++) csr[csrb + ex + j] = N;
  }
  __syncthreads();   // protect deg2/cnt2 for next grid-stride iteration
}

// fused layer tile: gather 64 rows of A*x -> LDS, GEMM, epilogues.
// Wfin == nullptr: store fp16 out (+ zero row N). Wfin != nullptr: z = out@Wfin + bfin (fp32).
__device__ __forceinline__ void dev_fused_tile(int rbase0,
    const _Float16* __restrict__ Xin,
    const _Float16* __restrict__ Wmain, const _Float16* __restrict__ Whd,
    const float* __restrict__ bias,
    const int* __restrict__ csr, const int2* __restrict__ sd,
    _Float16* __restrict__ Out, int N, int layer,
    const float* __restrict__ bc, const float* __restrict__ bR,
    const float* __restrict__ bt, const float* __restrict__ pos_in,
    float* __restrict__ pos_o, float* __restrict__ R_o, float* __restrict__ t_o,
    const _Float16* __restrict__ Wfin, const float* __restrict__ bfin,
    float* __restrict__ Zout,
    _Float16* __restrict__ lg /*[64*136]*/, float* __restrict__ lheads /*[64*16]*/,
    float* __restrict__ ldeg /*[64]*/){
  const int tid  = threadIdx.x;
  const int wave = tid >> 6;
  const int lane = tid & 63;
  const int quad = lane >> 4;
  const int l16  = lane & 15;

  // ---- phase 1: gather-aggregate (wave w -> local rows w*16 .. w*16+15) ----
  {
    const int nbase = rbase0 + wave*16;
    int nn = nbase + (lane & 15);
    int2 sv = (nn < N) ? sd[nn] : make_int2(0, 0);
    const unsigned int* Xu = (const unsigned int*)Xin;
    for (int i = 0; i < 16; i++){
      int s0    = __builtin_amdgcn_readlane(sv.x, i);
      int dpack = __builtin_amdgcn_readlane(sv.y, i);
      int degp  = dpack & 0xffff;
      if (lane == 0) ldeg[wave*16 + i] = (float)(dpack >> 16);
      float acc0 = 0.f, acc1 = 0.f;
      for (int base = 0; base < degp; base += 64){
        int myidx = csr[s0 + base + lane];          // one coalesced load covers 64 edges
        int m = degp - base; m = (m < 64) ? m : 64; // multiple of 8
        for (int k = 0; k < m; k += 8){
          unsigned int v[8];
#pragma unroll
          for (int j = 0; j < 8; j++){
            int idx = __builtin_amdgcn_readlane(myidx, k + j);   // SGPR row index
            v[j] = Xu[(size_t)idx*64 + lane];
          }
#pragma unroll
          for (int j = 0; j < 8; j++){
            float2 f = __half22float2(*(__half2*)&v[j]);
            acc0 += f.x; acc1 += f.y;
          }
        }
      }
      __half2 ho = __floats2half2_rn(acc0, acc1);
      ((unsigned int*)&lg[(wave*16 + i)*136])[lane] = *(unsigned int*)&ho;
    }
  }
  __syncthreads();

  // ---- phase 2: MFMA GEMM. waves 0,1: cols 0-63; waves 2,3: cols 64-127 ----
  const int cthi = wave >> 1;
  half8 af[4][2];
#pragma unroll
  for (int kc = 0; kc < 4; kc++)
#pragma unroll
    for (int rt = 0; rt < 2; rt++){
      int rl = (wave & 1)*32 + rt*16 + l16;
      af[kc][rt] = *(const half8*)&lg[rl*136 + kc*32 + quad*8];
    }
  __syncthreads();   // all lg reads done before out staging overwrites it

  floatx4 acc[2][4] = {};
#pragma unroll
  for (int kc = 0; kc < 4; kc++)
#pragma unroll
    for (int ct = 0; ct < 4; ct++){
      half8 bf = *(const half8*)(Wmain + (size_t)((cthi*4 + ct)*16 + l16)*128 + kc*32 + quad*8);
      acc[0][ct] = __builtin_amdgcn_mfma_f32_16x16x32_f16(af[kc][0], bf, acc[0][ct], 0, 0, 0);
      acc[1][ct] = __builtin_amdgcn_mfma_f32_16x16x32_f16(af[kc][1], bf, acc[1][ct], 0, 0, 0);
    }

  // ---- stage out to LDS (deg-scaled bias) ----
#pragma unroll
  for (int rt = 0; rt < 2; rt++){
    float dgv[4];
#pragma unroll
    for (int reg = 0; reg < 4; reg++)
      dgv[reg] = ldeg[(wave & 1)*32 + rt*16 + quad*4 + reg];
#pragma unroll
    for (int ct = 0; ct < 4; ct++){
      int col = (cthi*4 + ct)*16 + l16;
      float b = bias[col];
#pragma unroll
      for (int reg = 0; reg < 4; reg++){
        int rl = (wave & 1)*32 + rt*16 + quad*4 + reg;
        lg[rl*136 + col] = (_Float16)(acc[rt][ct][reg] + b*dgv[reg]);
      }
    }
  }
  __syncthreads();

  if (Wfin == nullptr){
    // ---- phase 3a: coalesced fp16 store (+ zero row N) ----
#pragma unroll
    for (int i = 0; i < 4; i++){
      int idx8 = i*256 + tid;
      int row = idx8 >> 4, c8 = idx8 & 15;
      int gr = rbase0 + row;
      if (gr < N){
        *(half8*)(Out + (size_t)gr*128 + c8*8) = *(const half8*)&lg[row*136 + c8*8];
      } else if (gr == N){
        half8 z = {};
        *(half8*)(Out + (size_t)gr*128 + c8*8) = z;
      }
    }
  } else {
    // ---- phase 3a': fused final GEMM  z = out @ Wfin + bfin, fp32 direct store ----
    half8 zf[4][2];
#pragma unroll
    for (int kc = 0; kc < 4; kc++)
#pragma unroll
      for (int rt = 0; rt < 2; rt++){
        int rl = (wave & 1)*32 + rt*16 + l16;
        zf[kc][rt] = *(const half8*)&lg[rl*136 + kc*32 + quad*8];
      }
    floatx4 zacc[2][4] = {};
#pragma unroll
    for (int kc = 0; kc < 4; kc++)
#pragma unroll
      for (int ct = 0; ct < 4; ct++){
        half8 bf = *(const half8*)(Wfin + (size_t)((cthi*4 + ct)*16 + l16)*128 + kc*32 + quad*8);
        zacc[0][ct] = __builtin_amdgcn_mfma_f32_16x16x32_f16(zf[kc][0], bf, zacc[0][ct], 0, 0, 0);
        zacc[1][ct] = __builtin_amdgcn_mfma_f32_16x16x32_f16(zf[kc][1], bf, zacc[1][ct], 0, 0, 0);
      }
#pragma unroll
    for (int rt = 0; rt < 2; rt++)
#pragma unroll
      for (int ct = 0; ct < 4; ct++){
        int col = (cthi*4 + ct)*16 + l16;
        float b = bfin[col];
#pragma unroll
        for (int reg = 0; reg < 4; reg++){
          int gr = rbase0 + (wave & 1)*32 + rt*16 + quad*4 + reg;
          if (gr < N) Zout[(size_t)gr*128 + col] = zacc[rt][ct][reg] + b;
        }
      }
  }

  // ---- phase 3b: head GEMM out @ Whd (wave w -> row-tile w) ----
  {
    floatx4 hacc = {};
#pragma unroll
    for (int kc = 0; kc < 4; kc++){
      half8 ha = *(const half8*)&lg[(wave*16 + l16)*136 + kc*32 + quad*8];
      half8 bf = *(const half8*)(Whd + (size_t)l16*128 + kc*32 + quad*8);
      hacc = __builtin_amdgcn_mfma_f32_16x16x32_f16(ha, bf, hacc, 0, 0, 0);
    }
#pragma unroll
    for (int reg = 0; reg < 4; reg++)
      lheads[(wave*16 + quad*4 + reg)*16 + l16] = hacc[reg];
  }
  __syncthreads();

  // ---- phase 4: SE(3) epilogue ----
  if (tid < 64){
    int n = rbase0 + tid;
    if (n < N){
      float ds[13];
#pragma unroll
      for (int c = 0; c < 13; c++) ds[c] = lheads[tid*16 + c];
      se3_node_ds(n, ds, bc, bR, bt, pos_in, pos_o, R_o, t_o, layer);
    }
  }
  __syncthreads();   // protect lg/lheads/ldeg for next grid-stride iteration
}

// ================= cooperative mega-kernel =============================================
struct MegaArgs {
  const float* x0; const float* pos; const int* src; const int* dst;
  const float* Wl; const float* Wf; const float* Wc; const float* WR; const float* Wt;
  const float* bl; const float* bc; const float* bR; const float* bt; const float* bf;
  _Float16* bufA; _Float16* bufB; _Float16* wTx; _Float16* wHd;
  int2* sd; int* cursor; int* binned; int* csr;
  float* z_out; float* pos_o; float* R_o; float* t_o;
  int N, E, nbuck, capB, capC, binB, fusedTiles;
};

__launch_bounds__(256)
__global__ void k_mega(MegaArgs a){
  cg::grid_group grid = cg::this_grid();
  __shared__ __align__(16) unsigned char smem[22016];
  const int tid = threadIdx.x;

  // ---- phase A: edge binning | x cvt | weight prep (independent, one phase) ----
  {
    int* cnt = (int*)smem;
    int* segbase = cnt + 512;
    for (int bb = blockIdx.x; bb < a.binB; bb += gridDim.x)
      dev_bin_block(bb, a.src, a.dst, a.E, a.nbuck, a.capB, a.cursor, a.binned, cnt, segbase);
  }
  {
    const int totc = (a.N + 1)*16;
    for (int c = blockIdx.x*256 + tid; c < totc; c += gridDim.x*256)
      dev_cvt_chunk(c, a.x0, a.bufA, a.N);
    const int totp = 4*128*128 + 3*16*128;
    for (int t = blockIdx.x*256 + tid; t < totp; t += gridDim.x*256)
      dev_prep_elem(t, a.Wl, a.Wf, a.Wc, a.WR, a.Wt, a.wTx, a.wHd);
  }
  grid.sync();

  // ---- phase B: per-bucket CSR build ----
  {
    int* deg2 = (int*)smem;
    int* lst2 = deg2 + BN*8;
    int* cnt2 = lst2 + BN*8;
    int* scn  = cnt2 + BN*8;
    for (int b = blockIdx.x; b < a.nbuck; b += gridDim.x)
      dev_build_block(b, a.binned, a.cursor, a.N, a.capB, a.capC, a.sd, a.csr,
                      deg2, lst2, cnt2, scn);
  }
  grid.sync();

  // ---- phases C/D/E: the 3 layers (layer 2 with fused final GEMM) ----
  _Float16* lg   = (_Float16*)smem;
  float* lheads  = (float*)(smem + 64*136*2);
  float* ldeg    = (float*)(smem + 64*136*2 + 64*16*4);
  const _Float16* xi = a.bufA;
  _Float16* xo = a.bufB;
#pragma unroll 1
  for (int layer = 0; layer < 3; layer++){
    const _Float16* Wm = a.wTx + (size_t)layer*16384;
    const _Float16* Wh = a.wHd + (size_t)layer*2048;
    const float* bi = a.bl + (size_t)layer*128;
    const _Float16* Wfin = (layer == 2) ? (a.wTx + (size_t)3*16384) : nullptr;
    for (int tb = blockIdx.x; tb < a.fusedTiles; tb += gridDim.x)
      dev_fused_tile(tb*64, xi, Wm, Wh, bi, a.csr, a.sd, xo, a.N, layer,
                     a.bc + layer, a.bR + (size_t)layer*9, a.bt + (size_t)layer*3,
                     a.pos, a.pos_o, a.R_o, a.t_o,
                     Wfin, a.bf, a.z_out, lg, lheads, ldeg);
    if (layer < 2) grid.sync();
    const _Float16* tsw = xi; xi = xo; xo = (_Float16*)tsw;
  }
}

// ================= fallback (R7) kernels ===============================================
__launch_bounds__(256)
__global__ void k_prebin(const float* __restrict__ x, _Float16* __restrict__ o, int N,
                         const float* __restrict__ Wl, const float* __restrict__ Wf,
                         const float* __restrict__ Wc, const float* __restrict__ WR,
                         const float* __restrict__ Wt, _Float16* __restrict__ wTx,
                         _Float16* __restrict__ wHd,
                         const int* __restrict__ src, const int* __restrict__ dst,
                         int E, int nbuck, int capB,
                         int* __restrict__ cursor, int* __restrict__ binned,
                         int cvtB, int prepB){
  __shared__ int cnt[512];
  __shared__ int segbase[512];
  const int b = blockIdx.x, tid = threadIdx.x;
  if (b < cvtB){
    int c = b*256 + tid;
    if (c < (N+1)*16) dev_cvt_chunk(c, x, o, N);
    return;
  }
  if (b < cvtB + prepB){
    dev_prep_elem((b - cvtB)*256 + tid, Wl, Wf, Wc, WR, Wt, wTx, wHd);
    return;
  }
  dev_bin_block(b - cvtB - prepB, src, dst, E, nbuck, capB, cursor, binned, cnt, segbase);
}

__launch_bounds__(256)
__global__ void k_build(const int* __restrict__ binned, const int* __restrict__ cursor,
                        int N, int capB, int capC,
                        int2* __restrict__ sd, int* __restrict__ csr){
  __shared__ int deg2[BN*8];
  __shared__ int lst2[BN*8];
  __shared__ int cnt2[BN*8];
  __shared__ int scn[BN];
  dev_build_block(blockIdx.x, binned, cursor, N, capB, capC, sd, csr, deg2, lst2, cnt2, scn);
}

__launch_bounds__(256)
__global__ void k_fused(const _Float16* __restrict__ Xin, const _Float16* __restrict__ Wmain,
                        const _Float16* __restrict__ Whd, const float* __restrict__ bias,
                        const int* __restrict__ csr, const int2* __restrict__ sd,
                        _Float16* __restrict__ Out, int N, int layer,
                        const float* __restrict__ bc, const float* __restrict__ bR,
                        const float* __restrict__ bt, const float* __restrict__ pos_in,
                        float* __restrict__ pos_o, float* __restrict__ R_o,
                        float* __restrict__ t_o){
  __shared__ __align__(16) _Float16 lg[64*136];
  __shared__ __align__(16) float lheads[64*16];
  __shared__ float ldeg[64];
  dev_fused_tile(blockIdx.x*64, Xin, Wmain, Whd, bias, csr, sd, Out, N, layer,
                 bc, bR, bt, pos_in, pos_o, R_o, t_o,
                 nullptr, nullptr, nullptr, lg, lheads, ldeg);
}

__launch_bounds__(256)
__global__ void k_fused_fin(const _Float16* __restrict__ Xin, const _Float16* __restrict__ Wmain,
                        const _Float16* __restrict__ Whd, const float* __restrict__ bias,
                        const int* __restrict__ csr, const int2* __restrict__ sd,
                        int N, int layer,
                        const float* __restrict__ bc, const float* __restrict__ bR,
                        const float* __restrict__ bt, const float* __restrict__ pos_in,
                        float* __restrict__ pos_o, float* __restrict__ R_o,
                        float* __restrict__ t_o,
                        const _Float16* __restrict__ Wfin, const float* __restrict__ bfin,
                        float* __restrict__ Zout){
  __shared__ __align__(16) _Float16 lg[64*136];
  __shared__ __align__(16) float lheads[64*16];
  __shared__ float ldeg[64];
  dev_fused_tile(blockIdx.x*64, Xin, Wmain, Whd, bias, csr, sd, nullptr, N, layer,
                 bc, bR, bt, pos_in, pos_o, R_o, t_o,
                 Wfin, bfin, Zout, lg, lheads, ldeg);
}

extern "C" void kernel_launch(void* const* d_in, const int* in_sizes, int n_in,
                              void* d_out, int out_size, void* d_ws, size_t ws_size,
                              hipStream_t stream){
  const float* x0  = (const float*)d_in[0];
  const float* pos = (const float*)d_in[1];
  const int*   ei  = (const int*)d_in[2];
  const float* Wl  = (const float*)d_in[3];
  const float* bl  = (const float*)d_in[4];
  const float* Wc  = (const float*)d_in[5];
  const float* bc  = (const float*)d_in[6];
  const float* WR  = (const float*)d_in[7];
  const float* bR  = (const float*)d_in[8];
  const float* Wt  = (const float*)d_in[9];
  const float* bt  = (const float*)d_in[10];
  const float* Wf  = (const float*)d_in[11];
  const float* bf  = (const float*)d_in[12];

  const int N = in_sizes[0] / 128;
  const int E = in_sizes[2] / 2;
  const int* srcp = ei;
  const int* dstp = ei + E;

  float* z_out = (float*)d_out;
  float* pos_o = z_out + (size_t)N*128;
  float* R_o   = pos_o + (size_t)N*3;
  float* t_o   = R_o   + (size_t)N*9;

  const int nbuck = (N + BN - 1) >> BSH;
  const int capB  = (((E + nbuck - 1)/nbuck)*5/4 + 256 + 63) & ~63;
  const int capC  = capB + BN*7;

  char* ws = (char*)d_ws;
  size_t off = 0;
  auto alloc = [&](size_t bytes)->char*{
    char* p = ws + off; off += (bytes + 511) & ~(size_t)511; return p;
  };
  _Float16* bufA = (_Float16*)alloc((size_t)(N+1)*128*2);
  _Float16* bufB = (_Float16*)alloc((size_t)(N+1)*128*2);
  _Float16* wTx  = (_Float16*)alloc((size_t)4*128*128*2);
  _Float16* wHd  = (_Float16*)alloc((size_t)3*16*128*2);
  int2*  sd     = (int2*) alloc((size_t)N*8);
  int*   cursor = (int*)  alloc((size_t)nbuck*4);
  int*   binned = (int*)  alloc((size_t)nbuck*capB*4);
  int*   csr    = (int*)  alloc((size_t)nbuck*capC*4);

  const int cvtB = ((N+1)*16 + 255)/256;
  const int prep_total = 4*128*128 + 3*16*128;
  const int prepB = (prep_total + 255)/256;
  const int binB  = (E + 4095)/4096;
  const int fused_blocks = (N + 64) >> 6;

  hipMemsetAsync(cursor, 0, (size_t)nbuck*4, stream);

  // ---- try the cooperative mega-kernel; fall back to R7 multi-launch on any failure ----
  bool coop_ok = false;
  {
    int perCU = 0;
    if (hipOccupancyMaxActiveBlocksPerMultiprocessor(&perCU, k_mega, 256, 0) == hipSuccess
        && perCU > 0){
      int dev = 0;
      (void)hipGetDevice(&dev);
      int nCU = 0;
      if (hipDeviceGetAttribute(&nCU, hipDeviceAttributeMultiprocessorCount, dev) != hipSuccess
          || nCU <= 0) nCU = 256;
      int G = fused_blocks;
      long cap = (long)perCU * nCU;
      if ((long)G > cap) G = (int)cap;
      if (G > 0){
        MegaArgs ma;
        ma.x0 = x0; ma.pos = pos; ma.src = srcp; ma.dst = dstp;
        ma.Wl = Wl; ma.Wf = Wf; ma.Wc = Wc; ma.WR = WR; ma.Wt = Wt;
        ma.bl = bl; ma.bc = bc; ma.bR = bR; ma.bt = bt; ma.bf = bf;
        ma.bufA = bufA; ma.bufB = bufB; ma.wTx = wTx; ma.wHd = wHd;
        ma.sd = sd; ma.cursor = cursor; ma.binned = binned; ma.csr = csr;
        ma.z_out = z_out; ma.pos_o = pos_o; ma.R_o = R_o; ma.t_o = t_o;
        ma.N = N; ma.E = E; ma.nbuck = nbuck; ma.capB = capB; ma.capC = capC;
        ma.binB = binB; ma.fusedTiles = fused_blocks;
        void* params[] = { &ma };
        if (hipLaunchCooperativeKernel(k_mega, dim3(G), dim3(256), params, 0u, stream)
            == hipSuccess)
          coop_ok = true;
      }
    }
  }

  if (!coop_ok){
    // ---- R7 fallback path ----
    k_prebin<<<dim3(cvtB + prepB + binB), dim3(256), 0, stream>>>(
        x0, bufA, N, Wl, Wf, Wc, WR, Wt, wTx, wHd,
        srcp, dstp, E, nbuck, capB, cursor, binned, cvtB, prepB);
    k_build<<<dim3(nbuck), dim3(256), 0, stream>>>(binned, cursor, N, capB, capC, sd, csr);
    k_fused<<<dim3(fused_blocks), dim3(256), 0, stream>>>(
        bufA, wTx, wHd, bl, csr, sd, bufB, N, 0,
        bc, bR, bt, pos, pos_o, R_o, t_o);
    k_fused<<<dim3(fused_blocks), dim3(256), 0, stream>>>(
        bufB, wTx + (size_t)16384, wHd + (size_t)2048, bl + 128, csr, sd, bufA, N, 1,
        bc + 1, bR + 9, bt + 3, pos, pos_o, R_o, t_o);
    k_fused_fin<<<dim3(fused_blocks), dim3(256), 0, stream>>>(
        bufA, wTx + (size_t)2*16384, wHd + (size_t)2*2048, bl + 256, csr, sd, N, 2,
        bc + 2, bR + 18, bt + 6, pos, pos_o, R_o, t_o,
        wTx + (size_t)3*16384, bf, z_out);
  }
}

// Round 9
// 266.355 us; speedup vs baseline: 2.4864x; 2.4864x over previous
//
#include <hip/hip_runtime.h>
#include <hip/hip_fp16.h>

typedef _Float16 half8 __attribute__((ext_vector_type(8)));
typedef float floatx4 __attribute__((ext_vector_type(4)));

#define OSH 13            // src-octile shift for csr ordering (locality in gather)
#define BN  64            // nodes per bucket == fused tile size (build merges into layer 0)
#define BSH 6             // log2(BN)

// ---------------- QR: 3x3 Householder, LAPACK sgeqrf/sorgqr convention ----------------
__device__ inline void qr3_q(const double A[3][3], double Q[3][3]){
  double a[3][3];
#pragma unroll
  for (int r = 0; r < 3; r++)
#pragma unroll
    for (int c = 0; c < 3; c++) a[r][c] = A[r][c];

  double v1[3] = {1.0, 0.0, 0.0};
  double tau1 = 0.0;
  {
    double xn2 = a[1][0]*a[1][0] + a[2][0]*a[2][0];
    if (xn2 != 0.0){
      double alpha = a[0][0];
      double beta = -copysign(sqrt(alpha*alpha + xn2), alpha);
      tau1 = (beta - alpha) / beta;
      double inv = 1.0 / (alpha - beta);
      v1[1] = a[1][0] * inv;
      v1[2] = a[2][0] * inv;
#pragma unroll
      for (int c = 1; c < 3; c++){
        double w = a[0][c] + v1[1]*a[1][c] + v1[2]*a[2][c];
        double tw = tau1 * w;
        a[0][c] -= tw;
        a[1][c] -= tw * v1[1];
        a[2][c] -= tw * v1[2];
      }
    }
  }
  double tau2 = 0.0, v2 = 0.0;
  {
    double x2 = a[2][1];
    if (x2 != 0.0){
      double alpha = a[1][1];
      double beta = -copysign(sqrt(alpha*alpha + x2*x2), alpha);
      tau2 = (beta - alpha) / beta;
      v2 = x2 / (alpha - beta);
    }
  }
  double M[3][3] = {{1.0, 0.0, 0.0},
                    {0.0, 1.0 - tau2, -tau2*v2},
                    {0.0, -tau2*v2, 1.0 - tau2*v2*v2}};
#pragma unroll
  for (int c = 0; c < 3; c++){
    double w = v1[0]*M[0][c] + v1[1]*M[1][c] + v1[2]*M[2][c];
#pragma unroll
    for (int r = 0; r < 3; r++)
      Q[r][c] = M[r][c] - tau1 * v1[r] * w;
  }
}

// ---------------- SE(3) per-node epilogue from a local ds[13] ----------------
__device__ inline void se3_node_ds(int n, const float ds[13],
                                   const float* __restrict__ bc, const float* __restrict__ bR,
                                   const float* __restrict__ bt, const float* __restrict__ pos_in,
                                   float* __restrict__ pos_o, float* __restrict__ R_o,
                                   float* __restrict__ t_o, int layer){
  double A[3][3], Q[3][3];
#pragma unroll
  for (int r = 0; r < 3; r++)
#pragma unroll
    for (int c = 0; c < 3; c++)
      A[r][c] = (double)ds[1 + r*3 + c] + (double)bR[r*3 + c];
  qr3_q(A, Q);

  double pd = (double)ds[0] + (double)bc[0];
#pragma unroll
  for (int c = 0; c < 3; c++){
    double base = (layer == 0) ? (double)pos_in[n*3 + c] : (double)pos_o[n*3 + c];
    pos_o[n*3 + c] = (float)(base + pd);
  }

  if (layer == 0){
#pragma unroll
    for (int r = 0; r < 3; r++)
#pragma unroll
      for (int c = 0; c < 3; c++)
        R_o[n*9 + r*3 + c] = (float)Q[r][c];
  } else {
    double Rold[3][3];
#pragma unroll
    for (int r = 0; r < 3; r++)
#pragma unroll
      for (int c = 0; c < 3; c++)
        Rold[r][c] = (double)R_o[n*9 + r*3 + c];
#pragma unroll
    for (int r = 0; r < 3; r++)
#pragma unroll
      for (int c = 0; c < 3; c++){
        double s = Q[r][0]*Rold[0][c] + Q[r][1]*Rold[1][c] + Q[r][2]*Rold[2][c];
        R_o[n*9 + r*3 + c] = (float)s;
      }
  }
#pragma unroll
  for (int c = 0; c < 3; c++){
    double base = (layer == 0) ? 0.0 : (double)t_o[n*3 + c];
    t_o[n*3 + c] = (float)(base + (double)ds[10 + c] + (double)bt[c]);
  }
}

// ------------- merged pre-kernel: cvt | weight prep | edge binning (one dispatch) -------
// blocks [0, cvtB): x fp32->fp16 (row N zeroed)
// blocks [cvtB, cvtB+prepB): wTx (4 x 128x128 [col][k]) + wHd (3 x 16x128)
// blocks [cvtB+prepB, ...): bin edges into BN-node buckets (cursor pre-zeroed via memset)
__launch_bounds__(256)
__global__ void k_prebin(const float* __restrict__ x, _Float16* __restrict__ o, int N,
                         const float* __restrict__ Wl, const float* __restrict__ Wf,
                         const float* __restrict__ Wc, const float* __restrict__ WR,
                         const float* __restrict__ Wt, _Float16* __restrict__ wTx,
                         _Float16* __restrict__ wHd,
                         const int* __restrict__ src, const int* __restrict__ dst,
                         int E, int nbuck, int capB,
                         int* __restrict__ cursor, int* __restrict__ binned,
                         int cvtB, int prepB){
  __shared__ int cnt[1024];
  __shared__ int segbase[1024];
  const int b = blockIdx.x;
  const int tid = threadIdx.x;

  if (b < cvtB){
    int c = b*256 + tid;               // half8 chunk id
    if (c >= (N+1)*16) return;
    int n = c >> 4;
    half8 h = {};
    if (n < N){
      const float* p = x + (size_t)c*8;
      float4 f0 = *(const float4*)p;
      float4 f1 = *(const float4*)(p + 4);
      h[0]=(_Float16)f0.x; h[1]=(_Float16)f0.y; h[2]=(_Float16)f0.z; h[3]=(_Float16)f0.w;
      h[4]=(_Float16)f1.x; h[5]=(_Float16)f1.y; h[6]=(_Float16)f1.z; h[7]=(_Float16)f1.w;
    }
    *(half8*)(o + (size_t)c*8) = h;
    return;
  }
  if (b < cvtB + prepB){
    int t = (b - cvtB)*256 + tid;
    if (t < 4*128*128){
      int l = t >> 14;
      int n = (t >> 7) & 127;
      int k = t & 127;
      const float* W = (l < 3) ? (Wl + (size_t)l*16384) : Wf;
      wTx[t] = (_Float16)W[k*128 + n];
    } else if (t < 4*128*128 + 3*16*128){
      int u = t - 4*128*128;
      int l = u >> 11;              // 16*128 = 2048 per slot
      int r = u & 2047;
      int n = r >> 7;
      int k = r & 127;
      float v = 0.f;
      if (n == 0)      v = Wc[(size_t)l*128 + k];
      else if (n < 10) v = WR[(size_t)l*1152 + k*9 + (n-1)];
      else if (n < 13) v = Wt[(size_t)l*384 + k*3 + (n-10)];
      wHd[u] = (_Float16)v;
    }
    return;
  }

  // ---- binning part ----
  const int bb = b - cvtB - prepB;
  for (int t = tid; t < nbuck; t += 256) cnt[t] = 0;
  __syncthreads();
  const int e0 = bb*4096 + tid;
  int pk[16], bk[16];
#pragma unroll
  for (int j = 0; j < 16; j++){
    int e = e0 + j*256;
    if (e < E){
      int d = dst[e], s = src[e];
      bk[j] = d >> BSH;
      pk[j] = (s << BSH) | (d & (BN-1));
      atomicAdd(&cnt[bk[j]], 1);
    } else bk[j] = -1;
  }
  __syncthreads();
  for (int t = tid; t < nbuck; t += 256){
    int c = cnt[t];
    if (c > 0) segbase[t] = t*capB + atomicAdd(&cursor[t], c);
    cnt[t] = 0;
  }
  __syncthreads();
#pragma unroll
  for (int j = 0; j < 16; j++){
    if (bk[j] >= 0){
      int ord = atomicAdd(&cnt[bk[j]], 1);
      binned[segbase[bk[j]] + ord] = pk[j];
    }
  }
}

// ---------------- layer-0 kernel: in-block CSR build + gather + GEMM + epilogues -------
// Block b == bucket b (BN=64 nodes). Build phase uses LDS aliased into the lg area, writes
// csr/sd to global for layers 1/2, keeps sd/deg in LDS for its own gather.
__launch_bounds__(256)
__global__ void k_fused0(const _Float16* __restrict__ Xin,
                         const _Float16* __restrict__ Wmain,
                         const _Float16* __restrict__ Whd,
                         const float* __restrict__ bias,
                         const int* __restrict__ binned, const int* __restrict__ cursor,
                         int capB, int capC,
                         int* __restrict__ csr, int2* __restrict__ sd,
                         _Float16* __restrict__ Out, int N,
                         const float* __restrict__ bc, const float* __restrict__ bR,
                         const float* __restrict__ bt, const float* __restrict__ pos_in,
                         float* __restrict__ pos_o, float* __restrict__ R_o,
                         float* __restrict__ t_o){
  __shared__ __align__(16) _Float16 lg[64][136];   // gather tile; build structs alias here
  __shared__ __align__(16) float lheads[64*16];
  __shared__ float ldeg[64];
  __shared__ int2 sdloc[64];

  const int tid  = threadIdx.x;
  const int wave = tid >> 6;
  const int lane = tid & 63;
  const int quad = lane >> 4;
  const int l16  = lane & 15;
  const int b    = blockIdx.x;          // bucket == tile
  const int rbase0 = b*64;

  // ---- phase 0: build this bucket's CSR (structs alias lg area, done before lg use) ----
  {
    int* deg2 = (int*)&lg[0][0];        // 512 ints
    int* lst2 = deg2 + 512;             // 512 ints
    int* cnt2 = lst2 + 512;             // 512 ints
    int* scn  = cnt2 + 512;             // 64 ints   (total 6400 B < 17408 B)
    for (int t = tid; t < 64*8; t += 256){ deg2[t] = 0; cnt2[t] = 0; }
    __syncthreads();
    const int nE = cursor[b];
    const int gbase = b*capB;
    for (int i = tid; i < nE; i += 256){
      int v = binned[gbase + i];
      int s = v >> BSH;
      int o = s >> OSH; if (o > 7) o = 7;
      atomicAdd(&deg2[((v & (BN-1)) << 3) + o], 1);
    }
    __syncthreads();
    int d0 = 0, p0 = 0;
    if (tid < 64){
#pragma unroll
      for (int o = 0; o < 8; o++) d0 += deg2[(tid << 3) + o];
      p0 = (d0+7)&~7;
      scn[tid] = p0;
    }
    __syncthreads();
#pragma unroll
    for (int off = 1; off < 64; off <<= 1){
      int add = 0;
      if (tid < 64 && tid >= off) add = scn[tid-off];
      __syncthreads();
      if (tid < 64) scn[tid] += add;
      __syncthreads();
    }
    const int csrb = b*capC;
    int ex = 0;
    if (tid < 64){
      ex = scn[tid] - p0;
      int off0 = ex;
#pragma unroll
      for (int o = 0; o < 8; o++){ lst2[(tid << 3) + o] = off0; off0 += deg2[(tid << 3) + o]; }
      int n0 = rbase0 + tid;
      int2 sv2 = make_int2(csrb + ex, (d0 << 16) | p0);
      sdloc[tid] = (n0 < N) ? sv2 : make_int2(0, 0);
      ldeg[tid] = (float)d0;
      if (n0 < N) sd[n0] = sv2;
    }
    __syncthreads();
    for (int i = tid; i < nE; i += 256){
      int v = binned[gbase + i];
      int dl = v & (BN-1), s = v >> BSH;
      int o = s >> OSH; if (o > 7) o = 7;
      int ord = atomicAdd(&cnt2[(dl << 3) + o], 1);
      csr[csrb + lst2[(dl << 3) + o] + ord] = s;
    }
    __syncthreads();
    if (tid < 64){
      for (int j = d0; j < p0; j++) csr[csrb + ex + j] = N;
    }
    __syncthreads();   // drains csr stores; build structs dead, lg free
  }

  // ---- phase 1: gather-aggregate (wave w -> local rows w*16 .. w*16+15) ----
  {
    int2 sv = sdloc[wave*16 + (lane & 15)];
    const unsigned int* Xu = (const unsigned int*)Xin;
    for (int i = 0; i < 16; i++){
      int s0    = __builtin_amdgcn_readlane(sv.x, i);
      int dpack = __builtin_amdgcn_readlane(sv.y, i);
      int degp  = dpack & 0xffff;
      float acc0 = 0.f, acc1 = 0.f;
      for (int base = 0; base < degp; base += 64){
        int myidx = csr[sdloc[wave*16 + i].x + base + lane];  // own-block csr, L1/L2 hot
        int m = degp - base; m = (m < 64) ? m : 64;           // multiple of 8
        for (int k = 0; k < m; k += 8){
          unsigned int v[8];
#pragma unroll
          for (int j = 0; j < 8; j++){
            int idx = __builtin_amdgcn_readlane(myidx, k + j);   // SGPR row index
            v[j] = Xu[(size_t)idx*64 + lane];
          }
#pragma unroll
          for (int j = 0; j < 8; j++){
            float2 f = __half22float2(*(__half2*)&v[j]);
            acc0 += f.x; acc1 += f.y;
          }
        }
      }
      __half2 ho = __floats2half2_rn(acc0, acc1);
      ((unsigned int*)&lg[wave*16 + i][0])[lane] = *(unsigned int*)&ho;
    }
  }
  __syncthreads();

  // ---- phase 2: MFMA GEMM. waves 0,1: cols 0-63; waves 2,3: cols 64-127 ----
  const int cthi = wave >> 1;
  half8 af[4][2];
#pragma unroll
  for (int kc = 0; kc < 4; kc++)
#pragma unroll
    for (int rt = 0; rt < 2; rt++){
      int rl = (wave & 1)*32 + rt*16 + l16;
      af[kc][rt] = *(const half8*)&lg[rl][kc*32 + quad*8];
    }
  __syncthreads();   // all lg reads done before out staging overwrites it

  floatx4 acc[2][4] = {};
#pragma unroll
  for (int kc = 0; kc < 4; kc++)
#pragma unroll
    for (int ct = 0; ct < 4; ct++){
      half8 bf = *(const half8*)(Wmain + (size_t)((cthi*4 + ct)*16 + l16)*128 + kc*32 + quad*8);
      acc[0][ct] = __builtin_amdgcn_mfma_f32_16x16x32_f16(af[kc][0], bf, acc[0][ct], 0, 0, 0);
      acc[1][ct] = __builtin_amdgcn_mfma_f32_16x16x32_f16(af[kc][1], bf, acc[1][ct], 0, 0, 0);
    }

  // ---- stage out to LDS (deg-scaled bias) ----
#pragma unroll
  for (int rt = 0; rt < 2; rt++){
    float dgv[4];
#pragma unroll
    for (int reg = 0; reg < 4; reg++)
      dgv[reg] = ldeg[(wave & 1)*32 + rt*16 + quad*4 + reg];
#pragma unroll
    for (int ct = 0; ct < 4; ct++){
      int col = (cthi*4 + ct)*16 + l16;
      float bv = bias[col];
#pragma unroll
      for (int reg = 0; reg < 4; reg++){
        int rl = (wave & 1)*32 + rt*16 + quad*4 + reg;
        lg[rl][col] = (_Float16)(acc[rt][ct][reg] + bv*dgv[reg]);
      }
    }
  }
  __syncthreads();

  // ---- phase 3a: coalesced global store (+ zero row N for csr padding) ----
#pragma unroll
  for (int i = 0; i < 4; i++){
    int idx8 = i*256 + tid;            // 1024 half8 chunks
    int row = idx8 >> 4, c8 = idx8 & 15;
    int gr = rbase0 + row;
    if (gr < N){
      *(half8*)(Out + (size_t)gr*128 + c8*8) = *(const half8*)&lg[row][c8*8];
    } else if (gr == N){
      half8 z = {};
      *(half8*)(Out + (size_t)gr*128 + c8*8) = z;
    }
  }

  // ---- phase 3b: head GEMM out @ Whd (wave w -> row-tile w) ----
  {
    floatx4 hacc = {};
#pragma unroll
    for (int kc = 0; kc < 4; kc++){
      half8 ha = *(const half8*)&lg[wave*16 + l16][kc*32 + quad*8];
      half8 bfh = *(const half8*)(Whd + (size_t)l16*128 + kc*32 + quad*8);
      hacc = __builtin_amdgcn_mfma_f32_16x16x32_f16(ha, bfh, hacc, 0, 0, 0);
    }
#pragma unroll
    for (int reg = 0; reg < 4; reg++)
      lheads[(wave*16 + quad*4 + reg)*16 + l16] = hacc[reg];
  }
  __syncthreads();

  // ---- phase 4: SE(3) epilogue (layer 0) ----
  if (tid < 64){
    int n = rbase0 + tid;
    if (n < N){
      float ds[13];
#pragma unroll
      for (int c = 0; c < 13; c++) ds[c] = lheads[tid*16 + c];
      se3_node_ds(n, ds, bc, bR, bt, pos_in, pos_o, R_o, t_o, 0);
    }
  }
}

// ---------------- layer-1 kernel (verbatim R7 k_fused): out = (A x) W + deg*b -----------
__launch_bounds__(256)
__global__ void k_fused(const _Float16* __restrict__ Xin,     // (N+1) rows fp16
                        const _Float16* __restrict__ Wmain,   // 128x128 [col][k]
                        const _Float16* __restrict__ Whd,     // 16x128  [col][k]
                        const float* __restrict__ bias,       // bl[layer] (128)
                        const int* __restrict__ csr, const int2* __restrict__ sd,
                        _Float16* __restrict__ Out,           // (N+1) rows fp16
                        int N, int layer,
                        const float* __restrict__ bc, const float* __restrict__ bR,
                        const float* __restrict__ bt, const float* __restrict__ pos_in,
                        float* __restrict__ pos_o, float* __restrict__ R_o,
                        float* __restrict__ t_o){
  __shared__ __align__(16) _Float16 lg[64][136];   // gather tile, reused for out staging
  __shared__ __align__(16) float lheads[64*16];
  __shared__ float ldeg[64];

  const int tid  = threadIdx.x;
  const int wave = tid >> 6;
  const int lane = tid & 63;
  const int quad = lane >> 4;
  const int l16  = lane & 15;
  const int rbase0 = blockIdx.x*64;

  // ---- phase 1: gather-aggregate (wave w -> local rows w*16 .. w*16+15) ----
  {
    const int nbase = rbase0 + wave*16;
    int nn = nbase + (lane & 15);
    int2 sv = (nn < N) ? sd[nn] : make_int2(0, 0);
    const unsigned int* Xu = (const unsigned int*)Xin;
    for (int i = 0; i < 16; i++){
      int s0    = __builtin_amdgcn_readlane(sv.x, i);
      int dpack = __builtin_amdgcn_readlane(sv.y, i);
      int degp  = dpack & 0xffff;
      if (lane == 0) ldeg[wave*16 + i] = (float)(dpack >> 16);
      float acc0 = 0.f, acc1 = 0.f;
      for (int base = 0; base < degp; base += 64){
        int myidx = csr[s0 + base + lane];          // one coalesced load covers 64 edges
        int m = degp - base; m = (m < 64) ? m : 64; // multiple of 8
        for (int k = 0; k < m; k += 8){
          unsigned int v[8];
#pragma unroll
          for (int j = 0; j < 8; j++){
            int idx = __builtin_amdgcn_readlane(myidx, k + j);   // SGPR row index
            v[j] = Xu[(size_t)idx*64 + lane];
          }
#pragma unroll
          for (int j = 0; j < 8; j++){
            float2 f = __half22float2(*(__half2*)&v[j]);
            acc0 += f.x; acc1 += f.y;
          }
        }
      }
      __half2 ho = __floats2half2_rn(acc0, acc1);
      ((unsigned int*)&lg[wave*16 + i][0])[lane] = *(unsigned int*)&ho;
    }
  }
  __syncthreads();

  // ---- phase 2: MFMA GEMM. waves 0,1: cols 0-63; waves 2,3: cols 64-127 ----
  const int cthi = wave >> 1;
  half8 af[4][2];
#pragma unroll
  for (int kc = 0; kc < 4; kc++)
#pragma unroll
    for (int rt = 0; rt < 2; rt++){
      int rl = (wave & 1)*32 + rt*16 + l16;
      af[kc][rt] = *(const half8*)&lg[rl][kc*32 + quad*8];
    }
  __syncthreads();   // all lg reads done before out staging overwrites it

  floatx4 acc[2][4] = {};
#pragma unroll
  for (int kc = 0; kc < 4; kc++)
#pragma unroll
    for (int ct = 0; ct < 4; ct++){
      half8 bf = *(const half8*)(Wmain + (size_t)((cthi*4 + ct)*16 + l16)*128 + kc*32 + quad*8);
      acc[0][ct] = __builtin_amdgcn_mfma_f32_16x16x32_f16(af[kc][0], bf, acc[0][ct], 0, 0, 0);
      acc[1][ct] = __builtin_amdgcn_mfma_f32_16x16x32_f16(af[kc][1], bf, acc[1][ct], 0, 0, 0);
    }

  // ---- stage out to LDS (deg-scaled bias) ----
#pragma unroll
  for (int rt = 0; rt < 2; rt++){
    float dgv[4];
#pragma unroll
    for (int reg = 0; reg < 4; reg++)
      dgv[reg] = ldeg[(wave & 1)*32 + rt*16 + quad*4 + reg];
#pragma unroll
    for (int ct = 0; ct < 4; ct++){
      int col = (cthi*4 + ct)*16 + l16;
      float b = bias[col];
#pragma unroll
      for (int reg = 0; reg < 4; reg++){
        int rl = (wave & 1)*32 + rt*16 + quad*4 + reg;
        lg[rl][col] = (_Float16)(acc[rt][ct][reg] + b*dgv[reg]);
      }
    }
  }
  __syncthreads();

  // ---- phase 3a: coalesced global store (half8 chunks), zero row N for csr padding ----
#pragma unroll
  for (int i = 0; i < 4; i++){
    int idx8 = i*256 + tid;            // 1024 half8 chunks
    int row = idx8 >> 4, c8 = idx8 & 15;
    int gr = rbase0 + row;
    if (gr < N){
      *(half8*)(Out + (size_t)gr*128 + c8*8) = *(const half8*)&lg[row][c8*8];
    } else if (gr == N){
      half8 z = {};
      *(half8*)(Out + (size_t)gr*128 + c8*8) = z;
    }
  }

  // ---- phase 3b: head GEMM out_l @ Whd (wave w -> row-tile w) ----
  {
    floatx4 hacc = {};
#pragma unroll
    for (int kc = 0; kc < 4; kc++){
      half8 ha = *(const half8*)&lg[wave*16 + l16][kc*32 + quad*8];
      half8 bf = *(const half8*)(Whd + (size_t)l16*128 + kc*32 + quad*8);
      hacc = __builtin_amdgcn_mfma_f32_16x16x32_f16(ha, bf, hacc, 0, 0, 0);
    }
#pragma unroll
    for (int reg = 0; reg < 4; reg++)
      lheads[(wave*16 + quad*4 + reg)*16 + l16] = hacc[reg];
  }
  __syncthreads();

  // ---- phase 4: SE(3) epilogue for this layer ----
  if (tid < 64){
    int n = rbase0 + tid;
    if (n < N){
      float ds[13];
#pragma unroll
      for (int c = 0; c < 13; c++) ds[c] = lheads[tid*16 + c];
      se3_node_ds(n, ds, bc, bR, bt, pos_in, pos_o, R_o, t_o, layer);
    }
  }
}

// ---------------- layer-2 kernel (verbatim R7): fused final GEMM z = out@Wf + bf --------
__launch_bounds__(256)
__global__ void k_fused_fin(const _Float16* __restrict__ Xin,
                        const _Float16* __restrict__ Wmain,
                        const _Float16* __restrict__ Whd,
                        const float* __restrict__ bias,
                        const int* __restrict__ csr, const int2* __restrict__ sd,
                        int N, int layer,
                        const float* __restrict__ bc, const float* __restrict__ bR,
                        const float* __restrict__ bt, const float* __restrict__ pos_in,
                        float* __restrict__ pos_o, float* __restrict__ R_o,
                        float* __restrict__ t_o,
                        const _Float16* __restrict__ Wfin,
                        const float* __restrict__ bfin,
                        float* __restrict__ Zout){
  __shared__ __align__(16) _Float16 lg[64][136];
  __shared__ __align__(16) float lheads[64*16];
  __shared__ float ldeg[64];

  const int tid  = threadIdx.x;
  const int wave = tid >> 6;
  const int lane = tid & 63;
  const int quad = lane >> 4;
  const int l16  = lane & 15;
  const int rbase0 = blockIdx.x*64;

  // ---- phase 1: gather-aggregate ----
  {
    const int nbase = rbase0 + wave*16;
    int nn = nbase + (lane & 15);
    int2 sv = (nn < N) ? sd[nn] : make_int2(0, 0);
    const unsigned int* Xu = (const unsigned int*)Xin;
    for (int i = 0; i < 16; i++){
      int s0    = __builtin_amdgcn_readlane(sv.x, i);
      int dpack = __builtin_amdgcn_readlane(sv.y, i);
      int degp  = dpack & 0xffff;
      if (lane == 0) ldeg[wave*16 + i] = (float)(dpack >> 16);
      float acc0 = 0.f, acc1 = 0.f;
      for (int base = 0; base < degp; base += 64){
        int myidx = csr[s0 + base + lane];
        int m = degp - base; m = (m < 64) ? m : 64;
        for (int k = 0; k < m; k += 8){
          unsigned int v[8];
#pragma unroll
          for (int j = 0; j < 8; j++){
            int idx = __builtin_amdgcn_readlane(myidx, k + j);
            v[j] = Xu[(size_t)idx*64 + lane];
          }
#pragma unroll
          for (int j = 0; j < 8; j++){
            float2 f = __half22float2(*(__half2*)&v[j]);
            acc0 += f.x; acc1 += f.y;
          }
        }
      }
      __half2 ho = __floats2half2_rn(acc0, acc1);
      ((unsigned int*)&lg[wave*16 + i][0])[lane] = *(unsigned int*)&ho;
    }
  }
  __syncthreads();

  // ---- phase 2: MFMA GEMM ----
  const int cthi = wave >> 1;
  half8 af[4][2];
#pragma unroll
  for (int kc = 0; kc < 4; kc++)
#pragma unroll
    for (int rt = 0; rt < 2; rt++){
      int rl = (wave & 1)*32 + rt*16 + l16;
      af[kc][rt] = *(const half8*)&lg[rl][kc*32 + quad*8];
    }
  __syncthreads();

  floatx4 acc[2][4] = {};
#pragma unroll
  for (int kc = 0; kc < 4; kc++)
#pragma unroll
    for (int ct = 0; ct < 4; ct++){
      half8 bf = *(const half8*)(Wmain + (size_t)((cthi*4 + ct)*16 + l16)*128 + kc*32 + quad*8);
      acc[0][ct] = __builtin_amdgcn_mfma_f32_16x16x32_f16(af[kc][0], bf, acc[0][ct], 0, 0, 0);
      acc[1][ct] = __builtin_amdgcn_mfma_f32_16x16x32_f16(af[kc][1], bf, acc[1][ct], 0, 0, 0);
    }

#pragma unroll
  for (int rt = 0; rt < 2; rt++){
    float dgv[4];
#pragma unroll
    for (int reg = 0; reg < 4; reg++)
      dgv[reg] = ldeg[(wave & 1)*32 + rt*16 + quad*4 + reg];
#pragma unroll
    for (int ct = 0; ct < 4; ct++){
      int col = (cthi*4 + ct)*16 + l16;
      float b = bias[col];
#pragma unroll
      for (int reg = 0; reg < 4; reg++){
        int rl = (wave & 1)*32 + rt*16 + quad*4 + reg;
        lg[rl][col] = (_Float16)(acc[rt][ct][reg] + b*dgv[reg]);
      }
    }
  }
  __syncthreads();

  // ---- phase 3a': fused final GEMM  z = out @ Wf + bf, direct fp32 store ----
  {
    half8 zf[4][2];
#pragma unroll
    for (int kc = 0; kc < 4; kc++)
#pragma unroll
      for (int rt = 0; rt < 2; rt++){
        int rl = (wave & 1)*32 + rt*16 + l16;
        zf[kc][rt] = *(const half8*)&lg[rl][kc*32 + quad*8];
      }
    floatx4 zacc[2][4] = {};
#pragma unroll
    for (int kc = 0; kc < 4; kc++)
#pragma unroll
      for (int ct = 0; ct < 4; ct++){
        half8 bf = *(const half8*)(Wfin + (size_t)((cthi*4 + ct)*16 + l16)*128 + kc*32 + quad*8);
        zacc[0][ct] = __builtin_amdgcn_mfma_f32_16x16x32_f16(zf[kc][0], bf, zacc[0][ct], 0, 0, 0);
        zacc[1][ct] = __builtin_amdgcn_mfma_f32_16x16x32_f16(zf[kc][1], bf, zacc[1][ct], 0, 0, 0);
      }
#pragma unroll
    for (int rt = 0; rt < 2; rt++)
#pragma unroll
      for (int ct = 0; ct < 4; ct++){
        int col = (cthi*4 + ct)*16 + l16;
        float b = bfin[col];
#pragma unroll
        for (int reg = 0; reg < 4; reg++){
          int gr = rbase0 + (wave & 1)*32 + rt*16 + quad*4 + reg;
          if (gr < N) Zout[(size_t)gr*128 + col] = zacc[rt][ct][reg] + b;
        }
      }
  }

  // ---- phase 3b: head GEMM ----
  {
    floatx4 hacc = {};
#pragma unroll
    for (int kc = 0; kc < 4; kc++){
      half8 ha = *(const half8*)&lg[wave*16 + l16][kc*32 + quad*8];
      half8 bf = *(const half8*)(Whd + (size_t)l16*128 + kc*32 + quad*8);
      hacc = __builtin_amdgcn_mfma_f32_16x16x32_f16(ha, bf, hacc, 0, 0, 0);
    }
#pragma unroll
    for (int reg = 0; reg < 4; reg++)
      lheads[(wave*16 + quad*4 + reg)*16 + l16] = hacc[reg];
  }
  __syncthreads();

  // ---- phase 4: SE(3) epilogue ----
  if (tid < 64){
    int n = rbase0 + tid;
    if (n < N){
      float ds[13];
#pragma unroll
      for (int c = 0; c < 13; c++) ds[c] = lheads[tid*16 + c];
      se3_node_ds(n, ds, bc, bR, bt, pos_in, pos_o, R_o, t_o, layer);
    }
  }
}

extern "C" void kernel_launch(void* const* d_in, const int* in_sizes, int n_in,
                              void* d_out, int out_size, void* d_ws, size_t ws_size,
                              hipStream_t stream){
  const float* x0  = (const float*)d_in[0];
  const float* pos = (const float*)d_in[1];
  const int*   ei  = (const int*)d_in[2];
  const float* Wl  = (const float*)d_in[3];
  const float* bl  = (const float*)d_in[4];
  const float* Wc  = (const float*)d_in[5];
  const float* bc  = (const float*)d_in[6];
  const float* WR  = (const float*)d_in[7];
  const float* bR  = (const float*)d_in[8];
  const float* Wt  = (const float*)d_in[9];
  const float* bt  = (const float*)d_in[10];
  const float* Wf  = (const float*)d_in[11];
  const float* bf  = (const float*)d_in[12];

  const int N = in_sizes[0] / 128;
  const int E = in_sizes[2] / 2;
  const int* srcp = ei;
  const int* dstp = ei + E;

  float* z_out = (float*)d_out;
  float* pos_o = z_out + (size_t)N*128;
  float* R_o   = pos_o + (size_t)N*3;
  float* t_o   = R_o   + (size_t)N*9;

  const int nbuck = (N + BN - 1) >> BSH;                       // 64-node buckets
  const int capB  = (((E + nbuck - 1)/nbuck)*5/4 + 256 + 63) & ~63;
  const int capC  = capB + BN*7;

  char* ws = (char*)d_ws;
  size_t off = 0;
  auto alloc = [&](size_t bytes)->char*{
    char* p = ws + off; off += (bytes + 511) & ~(size_t)511; return p;
  };
  _Float16* bufA = (_Float16*)alloc((size_t)(N+1)*128*2);   // x16 / out1
  _Float16* bufB = (_Float16*)alloc((size_t)(N+1)*128*2);   // out0 (out2 never stored)
  _Float16* wTx  = (_Float16*)alloc((size_t)4*128*128*2);
  _Float16* wHd  = (_Float16*)alloc((size_t)3*16*128*2);
  int2*  sd     = (int2*) alloc((size_t)N*8);
  int*   cursor = (int*)  alloc((size_t)nbuck*4);
  int*   binned = (int*)  alloc((size_t)nbuck*capB*4);
  int*   csr    = (int*)  alloc((size_t)nbuck*capC*4);

  const int cvtB = ((N+1)*16 + 255)/256;
  const int prep_total = 4*128*128 + 3*16*128;
  const int prepB = (prep_total + 255)/256;
  const int binB  = (E + 4095)/4096;
  const int fused_blocks = (N + 64) >> 6;   // covers zero-pad row N; == nbuck here

  hipMemsetAsync(cursor, 0, (size_t)nbuck*4, stream);
  k_prebin<<<dim3(cvtB + prepB + binB), dim3(256), 0, stream>>>(
      x0, bufA, N, Wl, Wf, Wc, WR, Wt, wTx, wHd,
      srcp, dstp, E, nbuck, capB, cursor, binned, cvtB, prepB);

  // layer 0 (+ in-block CSR build): bufA -> bufB
  k_fused0<<<dim3(fused_blocks), dim3(256), 0, stream>>>(
      bufA, wTx, wHd, bl,
      binned, cursor, capB, capC, csr, sd,
      bufB, N,
      bc, bR, bt, pos, pos_o, R_o, t_o);
  // layer 1: bufB -> bufA
  k_fused<<<dim3(fused_blocks), dim3(256), 0, stream>>>(
      bufB, wTx + (size_t)16384, wHd + (size_t)2048, bl + 128,
      csr, sd, bufA, N, 1,
      bc + 1, bR + 9, bt + 3, pos, pos_o, R_o, t_o);
  // layer 2 (+ fused final GEMM): bufA -> z
  k_fused_fin<<<dim3(fused_blocks), dim3(256), 0, stream>>>(
      bufA, wTx + (size_t)2*16384, wHd + (size_t)2*2048, bl + 256,
      csr, sd, N, 2,
      bc + 2, bR + 18, bt + 6, pos, pos_o, R_o, t_o,
      wTx + (size_t)3*16384, bf, z_out);
}